// Round 4
// baseline (167.354 us; speedup 1.0000x reference)
//
#include <hip/hip_runtime.h>

// Koopman bilinear rollout: preds[b,t,d] = (z0 @ Kd^{t+1})[b,d], D=B=256, T=512.
// Kd = (I-A)^-1(I+A), A=0.5*dt*K, ||A||~0.01 -> order-4 Neumann (2 launches).
// Parallel-in-time: M_j=Kd^j (j=1..32, log-depth), W_i=Kd^{32i} (i=1..16,
// log-depth, W_1 aliases M_32), 16 checkpoints in one batched launch, 496
// remaining timesteps in one batched bf16-MFMA fill launch.
// Fill staging uses global_load_lds(16B) with linear LDS dest + pre-swizzled
// global source + XOR-swizzled ds_read (rule-21 pattern), double-buffered.

#define DD 256
#define TT 512
#define MATF (DD * DD)

typedef __attribute__((ext_vector_type(8))) short bf16x8;
typedef __attribute__((ext_vector_type(4))) float f32x4;

#define GLD16(g, l)                                                  \
    __builtin_amdgcn_global_load_lds(                                \
        (const __attribute__((address_space(1))) void*)(g),          \
        (__attribute__((address_space(3))) void*)(l), 16, 0, 0)

static __device__ __forceinline__ unsigned short f2bf(float f) {
    unsigned int u = __float_as_uint(f);
    u += 0x7fffu + ((u >> 16) & 1u);
    return (unsigned short)(u >> 16);
}

// A = 0.5*exp(log_dt)*K ; Zb0 = bf16(z0)
__global__ void prep_kernel(const float* __restrict__ K,
                            const float* __restrict__ log_dt,
                            const float* __restrict__ z0,
                            float* __restrict__ A,
                            unsigned short* __restrict__ Zb0) {
    int idx = blockIdx.x * blockDim.x + threadIdx.x;
    float c = 0.5f * expf(log_dt[0]);
    A[idx] = c * K[idx];
    if (Zb0) Zb0[idx] = f2bf(z0[idx]);
}

// MTb_j[c][k] = bf16(M_j[k][c])  (transpose+convert, 32x32 LDS tiles)
__global__ void mtrans_kernel(const float* __restrict__ Mtab,
                              unsigned short* __restrict__ MTb) {
    __shared__ float tle[32][33];
    int j = blockIdx.z;
    const float* M = Mtab + (size_t)j * MATF;
    unsigned short* MT = MTb + (size_t)j * MATF;
    int k0 = blockIdx.y * 32, c0 = blockIdx.x * 32;
    int tx = threadIdx.x, ty = threadIdx.y;  // 32 x 8
#pragma unroll
    for (int i = 0; i < 32; i += 8)
        tle[ty + i][tx] = M[(size_t)(k0 + ty + i) * DD + c0 + tx];
    __syncthreads();
#pragma unroll
    for (int i = 0; i < 32; i += 8)
        MT[(size_t)(c0 + ty + i) * DD + k0 + tx] = f2bf(tle[tx][ty + i]);
}

// ---- 32x32-tile f32 GEMM core: 256 threads, K=256, K_BLK=64, reg prefetch ----
__device__ __forceinline__ void g32_core(const float* __restrict__ Ab, int lda,
                                         const float* __restrict__ Bb, int ldb,
                                         int rowBase, int colBase, float acc[2][2]) {
    __shared__ __align__(16) float As[64 * 38];
    __shared__ __align__(16) float Bs[64 * 40];
    const int tid = threadIdx.x;
    const int tx = tid & 15, ty = tid >> 4;
    const int am = tid >> 4;
    const int ak = (tid & 15) << 2;
    const int bk = tid >> 3;
    const int bn = (tid & 7) << 2;

    acc[0][0] = acc[0][1] = acc[1][0] = acc[1][1] = 0.f;

    float4 pa0 = *(const float4*)(Ab + (size_t)(rowBase + am) * lda + ak);
    float4 pa1 = *(const float4*)(Ab + (size_t)(rowBase + am + 16) * lda + ak);
    float4 pb0 = *(const float4*)(Bb + (size_t)bk * ldb + colBase + bn);
    float4 pb1 = *(const float4*)(Bb + (size_t)(bk + 32) * ldb + colBase + bn);

    for (int k0 = 0; k0 < DD; k0 += 64) {
        As[(ak + 0) * 38 + am] = pa0.x;
        As[(ak + 1) * 38 + am] = pa0.y;
        As[(ak + 2) * 38 + am] = pa0.z;
        As[(ak + 3) * 38 + am] = pa0.w;
        As[(ak + 0) * 38 + am + 16] = pa1.x;
        As[(ak + 1) * 38 + am + 16] = pa1.y;
        As[(ak + 2) * 38 + am + 16] = pa1.z;
        As[(ak + 3) * 38 + am + 16] = pa1.w;
        *(float4*)(&Bs[bk * 40 + bn]) = pb0;
        *(float4*)(&Bs[(bk + 32) * 40 + bn]) = pb1;
        __syncthreads();
        if (k0 + 64 < DD) {
            pa0 = *(const float4*)(Ab + (size_t)(rowBase + am) * lda + k0 + 64 + ak);
            pa1 = *(const float4*)(Ab + (size_t)(rowBase + am + 16) * lda + k0 + 64 + ak);
            pb0 = *(const float4*)(Bb + (size_t)(bk + k0 + 64) * ldb + colBase + bn);
            pb1 = *(const float4*)(Bb + (size_t)(bk + 32 + k0 + 64) * ldb + colBase + bn);
        }
#pragma unroll
        for (int kk = 0; kk < 64; ++kk) {
            float2 a2 = *(const float2*)(&As[kk * 38 + (ty << 1)]);
            float2 b2 = *(const float2*)(&Bs[kk * 40 + (tx << 1)]);
            acc[0][0] = fmaf(a2.x, b2.x, acc[0][0]);
            acc[0][1] = fmaf(a2.x, b2.y, acc[0][1]);
            acc[1][0] = fmaf(a2.y, b2.x, acc[1][0]);
            acc[1][1] = fmaf(a2.y, b2.y, acc[1][1]);
        }
        __syncthreads();
    }
}

// EPI 0: C = acc
// EPI 1: C = acc (=A@A) ; C2 = 2I + 2E + 2acc   (Neumann stage 1, E = A)
// EPI 2: C = acc + I + 2E                        (Neumann stage 2, E = A)
template <int EPI>
__global__ void __launch_bounds__(256)
g32_kernel(const float* __restrict__ A, const float* __restrict__ B,
           float* __restrict__ C, const float* __restrict__ E,
           float* __restrict__ C2,
           int lda, int ldb, int ldc,
           long long sA, long long sB, long long sC) {
    float acc[2][2];
    const int rowBase = blockIdx.y << 5, colBase = blockIdx.x << 5;
    g32_core(A + blockIdx.z * sA, lda, B + blockIdx.z * sB, ldb, rowBase, colBase, acc);
    float* Cb = C + blockIdx.z * sC;
    const int r0 = rowBase + ((threadIdx.x >> 4) << 1);
    const int c0 = colBase + ((threadIdx.x & 15) << 1);
#pragma unroll
    for (int i = 0; i < 2; ++i) {
        int r = r0 + i;
        float2 v;
        if (EPI == 2) {
            float e0 = E[(size_t)r * DD + c0], e1 = E[(size_t)r * DD + c0 + 1];
            v.x = acc[i][0] + 2.f * e0 + (r == c0 ? 1.f : 0.f);
            v.y = acc[i][1] + 2.f * e1 + (r == c0 + 1 ? 1.f : 0.f);
        } else {
            v.x = acc[i][0];
            v.y = acc[i][1];
        }
        *(float2*)(Cb + (size_t)r * ldc + c0) = v;
        if (EPI == 1) {
            float e0 = E[(size_t)r * DD + c0], e1 = E[(size_t)r * DD + c0 + 1];
            float2 w;
            w.x = 2.f * acc[i][0] + 2.f * e0 + (r == c0 ? 2.f : 0.f);
            w.y = 2.f * acc[i][1] + 2.f * e1 + (r == c0 + 1 ? 2.f : 0.f);
            *(float2*)(C2 + (size_t)r * DD + c0) = w;
        }
    }
}

// Checkpoints (batched): Z_i = z0 @ W_i -> f32 out[:,32i-1,:], bf16 Zb[i] (i<16)
__global__ void __launch_bounds__(256)
chk32_kernel(const float* __restrict__ z0, const float* __restrict__ Wbase,
             float* __restrict__ out, unsigned short* __restrict__ Zb) {
    const int i = blockIdx.z + 1;  // 1..16
    float acc[2][2];
    const int rowBase = blockIdx.y << 5, colBase = blockIdx.x << 5;
    g32_core(z0, DD, Wbase + (size_t)blockIdx.z * MATF, DD, rowBase, colBase, acc);
    const int r0 = rowBase + ((threadIdx.x >> 4) << 1);
    const int c0 = colBase + ((threadIdx.x & 15) << 1);
    float* Of = out + (size_t)(32 * i - 1) * DD;
    unsigned short* Zo = (i < 16) ? Zb + (size_t)i * MATF : (unsigned short*)0;
#pragma unroll
    for (int ii = 0; ii < 2; ++ii) {
        int r = r0 + ii;
        float2 v;
        v.x = acc[ii][0];
        v.y = acc[ii][1];
        *(float2*)(Of + (size_t)r * (TT * DD) + c0) = v;
        if (Zo) {
            unsigned int w = (unsigned int)f2bf(v.x) | ((unsigned int)f2bf(v.y) << 16);
            *(unsigned int*)(Zo + (size_t)r * DD + c0) = w;
        }
    }
}

// Batched bf16 MFMA fill: out[:, i*32+j-1, :] = Zb[i] @ M_j  (i=0..15, j=1..31)
// 128x128 tile, 4 waves, double-buffered global_load_lds staging.
// LDS layout per buffer: 1024 chunks of 16B, chunk c at byte c*16 holds global
// chunk c ^ ((c>>3)&7) (8 chunks per 128B row) -> read side uses the proven
// XOR swizzle byte ^ ((row&7)<<4).
__global__ void __launch_bounds__(256)
fill_kernel(const unsigned short* __restrict__ Zb,
            const unsigned short* __restrict__ MTb,
            float* __restrict__ out) {
    __shared__ __align__(16) unsigned short As[2][128 * 64];
    __shared__ __align__(16) unsigned short Bs[2][128 * 64];
    const int bz = blockIdx.z;
    const int i = bz / 31;
    const int j = bz % 31 + 1;
    const int t = i * 32 + j - 1;
    const unsigned short* Zt = Zb + (size_t)i * MATF;         // [row][k]
    const unsigned short* MT = MTb + (size_t)(j - 1) * MATF;  // [col][k]
    float* C = out + (size_t)t * DD;                          // row stride TT*DD

    const int tid = threadIdx.x;
    const int lane = tid & 63, wid = tid >> 6;
    const int rowBase = blockIdx.y * 128, colBase = blockIdx.x * 128;
    const int wr = (wid >> 1) * 64, wc = (wid & 1) * 64;

    // per-lane staging geometry: chunk c = q*256 + wid*64 + lane
    int rowq[4], skq[4], ldsq[4];
#pragma unroll
    for (int q = 0; q < 4; ++q) {
        int c = q * 256 + wid * 64 + lane;
        int row = c >> 3;
        rowq[q] = row;
        skq[q] = ((c ^ (row & 7)) & 7) << 3;      // src k-offset in elements
        ldsq[q] = (q * 256 + wid * 64) << 3;      // wave-uniform LDS base (shorts)
    }

    f32x4 acc[4][4];
#pragma unroll
    for (int a = 0; a < 4; ++a)
#pragma unroll
        for (int b = 0; b < 4; ++b) acc[a][b] = (f32x4){0.f, 0.f, 0.f, 0.f};

    auto stage = [&](int buf, int k0) {
#pragma unroll
        for (int q = 0; q < 4; ++q) {
            GLD16(Zt + (size_t)(rowBase + rowq[q]) * DD + k0 + skq[q],
                  &As[buf][ldsq[q]]);
            GLD16(MT + (size_t)(colBase + rowq[q]) * DD + k0 + skq[q],
                  &Bs[buf][ldsq[q]]);
        }
    };

    stage(0, 0);
    __syncthreads();  // drains vmcnt (compiler emits waitcnt before s_barrier)

    int cur = 0;
    for (int r = 0; r < 4; ++r) {
        if (r < 3) stage(cur ^ 1, (r + 1) * 64);  // async loads into other buf
        const char* asb = (const char*)As[cur];
        const char* bsb = (const char*)Bs[cur];
#pragma unroll
        for (int ks = 0; ks < 2; ++ks) {
            bf16x8 af[4], bg[4];
            const int kk = ks * 32 + (lane >> 4) * 8;
#pragma unroll
            for (int f = 0; f < 4; ++f) {
                int rr = wr + f * 16 + (lane & 15);
                af[f] = *(const bf16x8*)(asb + ((rr * 128 + kk * 2) ^ ((rr & 7) << 4)));
                int cc = wc + f * 16 + (lane & 15);
                bg[f] = *(const bf16x8*)(bsb + ((cc * 128 + kk * 2) ^ ((cc & 7) << 4)));
            }
#pragma unroll
            for (int fr = 0; fr < 4; ++fr)
#pragma unroll
                for (int fc = 0; fc < 4; ++fc)
                    acc[fr][fc] = __builtin_amdgcn_mfma_f32_16x16x32_bf16(
                        af[fr], bg[fc], acc[fr][fc], 0, 0, 0);
        }
        __syncthreads();  // waves done reading cur AND next-buf loads landed
        cur ^= 1;
    }

#pragma unroll
    for (int fr = 0; fr < 4; ++fr) {
        int r0 = rowBase + wr + fr * 16 + (lane >> 4) * 4;
#pragma unroll
        for (int fc = 0; fc < 4; ++fc) {
            int c = colBase + wc + fc * 16 + (lane & 15);
#pragma unroll
            for (int ii = 0; ii < 4; ++ii)
                C[(size_t)(r0 + ii) * (TT * DD) + c] = acc[fr][fc][ii];
        }
    }
}

extern "C" void kernel_launch(void* const* d_in, const int* in_sizes, int n_in,
                              void* d_out, int out_size, void* d_ws, size_t ws_size,
                              hipStream_t stream) {
    const float* z0 = (const float*)d_in[0];
    const float* Kmat = (const float*)d_in[1];
    const float* log_dt = (const float*)d_in[2];
    float* out = (float*)d_out;

    dim3 blk(256);

    // ws layout: A | A2 | Bop | Mtab[47] (M_1..M_32, W_2..W_16; W_1 = M_32)
    //            | MTb[31] bf16 | Zb[16] bf16
    float* A = (float*)d_ws;
    float* A2 = A + MATF;
    float* Bop = A2 + MATF;
    float* Mtab = Bop + MATF;
    unsigned short* MTb = (unsigned short*)(Mtab + (size_t)47 * MATF);
    unsigned short* Zb = MTb + (size_t)31 * MATF;
    const size_t needA =
        (size_t)(3 + 47) * MATF * sizeof(float) + (size_t)(31 + 16) * MATF * 2;

    if (ws_size >= needA) {
        prep_kernel<<<MATF / 256, blk, 0, stream>>>(Kmat, log_dt, z0, A, Zb);

        dim3 g(8, 8, 1);
        // Neumann (order 4) in 2 GEMMs: A2 = A@A (+Bop epi); Kd = A2@Bop + I + 2A
        g32_kernel<1><<<g, blk, 0, stream>>>(A, A, A2, A, Bop, DD, DD, DD, 0, 0, 0);
        g32_kernel<2><<<g, blk, 0, stream>>>(A2, Bop, Mtab, A, (float*)0,
                                             DD, DD, DD, 0, 0, 0);

        // M powers: M_{q+p} = M_q @ M_p (log depth) -> M_1..M_32
        for (int p = 1; p < 32; p <<= 1)
            g32_kernel<0><<<dim3(8, 8, p), blk, 0, stream>>>(
                Mtab, Mtab + (size_t)(p - 1) * MATF, Mtab + (size_t)p * MATF,
                (const float*)0, (float*)0, DD, DD, DD, MATF, 0, MATF);

        // W powers: W_1 = M_32 (aliased); W_{q+p} = W_q @ W_p -> W_1..W_16
        float* Wb = Mtab + (size_t)31 * MATF;
        for (int p = 1; p < 16; p <<= 1)
            g32_kernel<0><<<dim3(8, 8, p), blk, 0, stream>>>(
                Wb, Wb + (size_t)(p - 1) * MATF, Wb + (size_t)p * MATF,
                (const float*)0, (float*)0, DD, DD, DD, MATF, 0, MATF);

        // bf16 transposed M table
        mtrans_kernel<<<dim3(8, 8, 31), dim3(32, 8), 0, stream>>>(Mtab, MTb);

        // All 16 checkpoints in one batched launch
        chk32_kernel<<<dim3(8, 8, 16), blk, 0, stream>>>(z0, Wb, out, Zb);

        // All 496 remaining timesteps in one batched MFMA launch
        fill_kernel<<<dim3(2, 2, 496), blk, 0, stream>>>(Zb, MTb, out);
        return;
    }

    // Minimal fallback (tiny ws): Kd in 4 matrices, then 512 chained GEMMs.
    float* Kd = Bop + MATF;
    prep_kernel<<<MATF / 256, blk, 0, stream>>>(Kmat, log_dt, z0, A,
                                                (unsigned short*)0);
    dim3 g(8, 8, 1);
    g32_kernel<1><<<g, blk, 0, stream>>>(A, A, A2, A, Bop, DD, DD, DD, 0, 0, 0);
    g32_kernel<2><<<g, blk, 0, stream>>>(A2, Bop, Kd, A, (float*)0, DD, DD, DD, 0, 0, 0);
    for (int t = 0; t < TT; ++t) {
        const float* Ain = (t == 0) ? z0 : out + (size_t)(t - 1) * DD;
        int lda = (t == 0) ? DD : TT * DD;
        g32_kernel<0><<<g, blk, 0, stream>>>(Ain, Kd, out + (size_t)t * DD,
                                             (const float*)0, (float*)0,
                                             lda, DD, TT * DD, 0, 0, 0);
    }
}